// Round 3
// baseline (1295.640 us; speedup 1.0000x reference)
//
#include <hip/hip_runtime.h>

#define NB 32
#define TT 2048
#define II 256
#define HH 512
#define LCH 8
#define NCH 256

typedef short s8v __attribute__((ext_vector_type(8)));
typedef short s4v __attribute__((ext_vector_type(4)));
typedef __bf16 bf8v __attribute__((ext_vector_type(8)));
typedef float f4v __attribute__((ext_vector_type(4)));

#define DEVI static __device__ __forceinline__

DEVI float bf2f(short s){ union{unsigned u; float f;} c; c.u = ((unsigned)(unsigned short)s) << 16; return c.f; }
DEVI short f2bf(float f){ union{float f; unsigned u;} c; c.f = f; unsigned u = c.u; u += 0x7FFF + ((u >> 16) & 1); return (short)(u >> 16); }
DEVI f4v fzero(){ f4v z = {0.0f,0.0f,0.0f,0.0f}; return z; }

DEVI f4v mfma16(s8v a, s8v b, f4v c){
  union{ s8v s; bf8v b; } ua, ub; ua.s = a; ub.s = b;
  return __builtin_amdgcn_mfma_f32_16x16x32_bf16(ua.b, ub.b, c, 0, 0, 0);
}

DEVI s8v packbf(f4v lo, f4v hi){
  s8v o;
  o[0]=f2bf(lo[0]); o[1]=f2bf(lo[1]); o[2]=f2bf(lo[2]); o[3]=f2bf(lo[3]);
  o[4]=f2bf(hi[0]); o[5]=f2bf(hi[1]); o[6]=f2bf(hi[2]); o[7]=f2bf(hi[3]);
  return o;
}

// A-frag / B^T-frag from global: lane holds M[row0 + (lane&15)][k0 + (lane>>4)*8 + 0..7]
// full-line efficient: each of the 16 rows contributes one fully-consumed 64B line.
DEVI s8v ldfrag_bf(const short* base, int row0, int ld, int k0, int lane){
  const short* p = base + (size_t)(row0 + (lane & 15)) * ld + k0 + ((lane >> 4) << 3);
  return *(const s8v*)p;
}
DEVI s8v ldfrag_f32(const float* base, int row0, int ld, int k0, int lane){
  const float* p = base + (size_t)(row0 + (lane & 15)) * ld + k0 + ((lane >> 4) << 3);
  f4v lo = *(const f4v*)p;
  f4v hi = *(const f4v*)(p + 4);
  return packbf(lo, hi);
}
// A-frag over x with row = n (stride TT*II), fixed t
DEVI s8v ldfragX(const float* x, int t, int n0, int k0, int lane){
  const float* p = x + ((size_t)(n0 + (lane & 15))*TT + t)*II + k0 + ((lane >> 4) << 3);
  f4v lo = *(const f4v*)p;
  f4v hi = *(const f4v*)(p + 4);
  return packbf(lo, hi);
}

// XOR swizzle for LDS state buffer (row stride 512 bf16 = 1024 B)
DEVI int swzoff(int row, int col){ return (row << 9) + ((((col >> 3) ^ (row & 7)) << 3) | (col & 7)); }

// lgkm-only barrier: does NOT drain vmcnt, so global loads/stores stay in flight
#define RAWBAR() asm volatile("s_waitcnt lgkmcnt(0)\n\ts_barrier" ::: "memory")

// ---------------- fp32 W_hh -> bf16 mats[0] + transpose matsT[0] ----------------
__global__ __launch_bounds__(256) void k_init_p1(const float* __restrict__ W,
                                                 short* __restrict__ mats, short* __restrict__ matsT){
  __shared__ short tile[64][65];
  int bx = blockIdx.x, by = blockIdx.y;
  int t = threadIdx.x;
  for(int i = 0; i < 16; ++i){
    int idx = t + 256*i;
    int rr = idx >> 6, cc = idx & 63;
    short v = f2bf(W[(size_t)(64*by + rr)*HH + 64*bx + cc]);
    tile[rr][cc] = v;
    mats[(size_t)(64*by + rr)*HH + 64*bx + cc] = v;
  }
  __syncthreads();
  for(int i = 0; i < 16; ++i){
    int idx = t + 256*i;
    int rr = idx >> 6, cc = idx & 63;
    matsT[(size_t)(64*bx + rr)*HH + 64*by + cc] = tile[cc][rr];
  }
}

// ---------------- fp32 -> bf16 elementwise (for W_ih) ----------------
__global__ __launch_bounds__(256) void k_cvt(const float* __restrict__ src, short* __restrict__ dst, int n){
  for(int i = blockIdx.x*256 + threadIdx.x; i < n; i += gridDim.x*256) dst[i] = f2bf(src[i]);
}

// ---------------- bf16 512x512 product C = A*B (Bt given), writes C and C^T ----------------
struct ProdArgs {
  const short* A[8]; const short* Bt[8]; short* C[8]; short* Ct[8];
};
__global__ __launch_bounds__(256) void k_prod(ProdArgs args){
  int bz = blockIdx.z;
  const short* A  = args.A[bz];
  const short* Bt = args.Bt[bz];
  short* C  = args.C[bz];
  short* Ct = args.Ct[bz];
  int wave = threadIdx.x >> 6, lane = threadIdx.x & 63;
  int mrow0 = blockIdx.x*64 + (wave & 1)*32;
  int ncol0 = blockIdx.y*128 + (wave >> 1)*64;
  f4v acc[2][4];
  for(int mi=0;mi<2;mi++) for(int j=0;j<4;j++) acc[mi][j] = fzero();
  for(int k0 = 0; k0 < HH; k0 += 32){
    s8v a0 = ldfrag_bf(A, mrow0,      HH, k0, lane);
    s8v a1 = ldfrag_bf(A, mrow0 + 16, HH, k0, lane);
    #pragma unroll
    for(int j = 0; j < 4; ++j){
      s8v b = ldfrag_bf(Bt, ncol0 + (j<<4), HH, k0, lane);
      acc[0][j] = mfma16(a0, b, acc[0][j]);
      acc[1][j] = mfma16(a1, b, acc[1][j]);
    }
  }
  int q = lane >> 4, c0 = lane & 15;
  for(int mi=0;mi<2;mi++) for(int j=0;j<4;j++) for(int r=0;r<4;r++){
    int row = mrow0 + (mi<<4) + (q<<2) + r;
    int col = ncol0 + (j<<4) + c0;
    short v = f2bf(acc[mi][j][r]);
    C [(size_t)row*HH + col] = v;
    Ct[(size_t)col*HH + row] = v;
  }
}

// ---------------- proj, t-major: block = one t; 32 n-rows x 512 cols, K=256 ----------------
// Output projF is FRAGMENT-MAJOR: [t][tid][32 bf16] so the scan reads its per-lane proj
// values as 4 contiguous 16B loads. Block t==0 also writes Y0[0] = initial + proj[:,0].
__global__ __launch_bounds__(512) void k_projT(const float* __restrict__ x, const short* __restrict__ Wb,
                                               const float* __restrict__ bih, const float* __restrict__ initial,
                                               short* __restrict__ projF, float* __restrict__ Y00){
  int t = blockIdx.x;
  int tid = threadIdx.x, wave = tid >> 6, lane = tid & 63;
  int q = lane >> 4, c0 = lane & 15;
  int ncol0 = wave << 6;
  f4v acc[2][4];
  #pragma unroll
  for(int mi=0;mi<2;mi++)
  #pragma unroll
  for(int j=0;j<4;j++) acc[mi][j] = fzero();
  #pragma unroll
  for(int kc = 0; kc < 8; ++kc){
    int k0 = kc << 5;
    s8v a0 = ldfragX(x, t, 0,  k0, lane);
    s8v a1 = ldfragX(x, t, 16, k0, lane);
    #pragma unroll
    for(int j = 0; j < 4; ++j){
      s8v bb = ldfrag_bf(Wb, ncol0 + (j<<4), II, k0, lane);
      acc[0][j] = mfma16(a0, bb, acc[0][j]);
      acc[1][j] = mfma16(a1, bb, acc[1][j]);
    }
  }
  float bv[4];
  #pragma unroll
  for(int j=0;j<4;++j) bv[j] = bih[ncol0 + (j<<4) + c0];
  s8v pv[4];
  #pragma unroll
  for(int mi=0;mi<2;++mi)
  #pragma unroll
  for(int j=0;j<4;++j)
  #pragma unroll
  for(int r=0;r<4;++r){
    int idx = (mi<<4) | (j<<2) | r;
    float v = acc[mi][j][r] + bv[j];
    pv[idx>>3][idx&7] = f2bf(v);
    if(t == 0){
      int n = (mi<<4) + (q<<2) + r;
      int col = ncol0 + (j<<4) + c0;
      Y00[(size_t)n*HH + col] = v + initial[(size_t)n*HH + col];
    }
  }
  short* dst = projF + (((size_t)t << 9) + tid)*32;
  #pragma unroll
  for(int g = 0; g < 4; ++g) *(s8v*)(dst + (g<<3)) = pv[g];
}

// ---------------- chunked scan: direct-reg W B-frags, no K-loop barriers ----------------
// PHASE 0: zero-init, emit chunk summaries Y0[c+1].  PHASE 1: init from true boundary
// Zin[c], write final hiddens (DUAL: both output copies) via coalesced LDS out-stage.
template<int PHASE, int DUAL>
__global__ __launch_bounds__(512) void k_scan(const short* __restrict__ projF,
                                              const short* __restrict__ Wb,
                                              const float* __restrict__ Zin,
                                              float* __restrict__ Yout,
                                              float* __restrict__ Yout2){
  __shared__ __align__(16) short st[NB*HH];                      // 32KB bf16 state (swizzled)
  __shared__ __align__(16) float fstage[PHASE==1 ? NB*HH : 4];   // PHASE1: 64KB fp32 out-stage
  int c = blockIdx.x;
  int tid = threadIdx.x, wave = tid >> 6, lane = tid & 63;
  int q = lane >> 4, c0 = lane & 15;
  int ncol0 = wave << 6;
  if constexpr(PHASE == 0){
    for(int i = tid; i < NB*HH; i += 512) st[i] = 0;
  } else {
    const float* Z = Zin + (size_t)c*NB*HH;
    #pragma unroll
    for(int rr = 0; rr < 8; ++rr){
      int fi = tid + (rr << 9);
      int rn = fi >> 7, col = (fi & 127) << 2;
      f4v v = *(const f4v*)(Z + (size_t)rn*HH + col);
      s4v sv; sv[0]=f2bf(v[0]); sv[1]=f2bf(v[1]); sv[2]=f2bf(v[2]); sv[3]=f2bf(v[3]);
      *(s4v*)(st + swzoff(rn, col)) = sv;
      if(c == 0){                                   // t = 0 slice
        *(f4v*)(Yout + ((size_t)rn*TT)*HH + col) = v;
        if(DUAL) *(f4v*)(Yout2 + ((size_t)rn*TT)*HH + col) = v;
      }
    }
  }
  RAWBAR();
  int tmax = min(LCH, TT - 1 - LCH*c);
  for(int tl = 1; tl <= tmax; ++tl){
    int t = LCH*c + tl;
    // per-lane proj fragment: 4 contiguous 16B loads (issued early, consumed in epilogue)
    const short* pb = projF + (((size_t)(t-1) << 9) + tid)*32;
    s8v pp[4];
    pp[0] = *(const s8v*)(pb);
    pp[1] = *(const s8v*)(pb + 8);
    pp[2] = *(const s8v*)(pb + 16);
    pp[3] = *(const s8v*)(pb + 24);
    f4v acc[2][4];
    #pragma unroll
    for(int mi=0;mi<2;mi++)
    #pragma unroll
    for(int j=0;j<4;j++) acc[mi][j] = fzero();
    // K-loop: A from stable LDS state, B direct from global (L2) — no barriers inside.
    #pragma unroll
    for(int kc = 0; kc < 16; ++kc){
      int k0 = kc << 5;
      int colb = k0 + (q << 3);
      s8v a0 = *(const s8v*)(st + swzoff(c0,      colb));
      s8v a1 = *(const s8v*)(st + swzoff(c0 + 16, colb));
      #pragma unroll
      for(int j = 0; j < 4; ++j){
        s8v bb = ldfrag_bf(Wb, ncol0 + (j<<4), HH, k0, lane);
        acc[0][j] = mfma16(a0, bb, acc[0][j]);
        acc[1][j] = mfma16(a1, bb, acc[1][j]);
      }
    }
    RAWBAR();                                       // B1: all st reads done -> safe to update
    #pragma unroll
    for(int mi=0;mi<2;++mi)
    #pragma unroll
    for(int j=0;j<4;++j)
    #pragma unroll
    for(int r=0;r<4;++r){
      int idx = (mi<<4) | (j<<2) | r;
      int rown = (mi<<4) + (q<<2) + r;
      int col  = ncol0 + (j<<4) + c0;
      float v = acc[mi][j][r] + bf2f(pp[idx>>3][idx&7]);
      st[swzoff(rown, col)] = f2bf(v);
      if constexpr(PHASE == 0){
        if(tl == LCH && c + 1 < NCH)
          Yout[((size_t)(c+1)*NB + rown)*HH + col] = v;   // chunk summary
      } else {
        fstage[rown*HH + col] = v;
      }
    }
    if constexpr(PHASE == 1){
      RAWBAR();                                     // B2: fstage + st visible
      #pragma unroll
      for(int rr = 0; rr < 8; ++rr){                // coalesced full-line stores; drain deferred
        int fi = tid + (rr << 9);
        int rn = fi >> 7, col = (fi & 127) << 2;
        f4v v = *(const f4v*)(fstage + (size_t)rn*HH + col);
        *(f4v*)(Yout + ((size_t)rn*TT + t)*HH + col) = v;
        if(DUAL) *(f4v*)(Yout2 + ((size_t)rn*TT + t)*HH + col) = v;
      }
      // fstage reads complete before next step's writes: separated by next B1 (lgkm+barrier)
    } else {
      RAWBAR();                                     // B2: st visible before next step's reads
    }
  }
}

// ---------------- Kogge-Stone level: Yout[i] = Yin[i] + Yin[i-s] @ As^T (direct-reg) ----------------
__global__ __launch_bounds__(512) void k_ks(const float* __restrict__ Yin, float* __restrict__ Yout,
                                            const short* __restrict__ As, int s){
  __shared__ __align__(16) float fstage[NB*HH];     // 64KB fp32 out-stage
  int i = blockIdx.x;
  int tid = threadIdx.x;
  if(i < s){
    const float* src = Yin + (size_t)i*NB*HH;
    float* dst = Yout + (size_t)i*NB*HH;
    for(int fi = tid; fi < NB*HH/4; fi += 512)
      *(f4v*)(dst + ((size_t)fi << 2)) = *(const f4v*)(src + ((size_t)fi << 2));
    return;
  }
  int wave = tid >> 6, lane = tid & 63;
  int q = lane >> 4, c0 = lane & 15;
  int ncol0 = wave << 6;
  const float* Xp = Yin + (size_t)(i - s)*NB*HH;
  const float* Xc = Yin + (size_t)i*NB*HH;
  float* Out = Yout + (size_t)i*NB*HH;
  f4v acc[2][4];
  #pragma unroll
  for(int mi=0;mi<2;mi++)
  #pragma unroll
  for(int j=0;j<4;j++) acc[mi][j] = fzero();
  #pragma unroll
  for(int kc = 0; kc < 16; ++kc){
    int k0 = kc << 5;
    s8v a0 = ldfrag_f32(Xp, 0,  HH, k0, lane);
    s8v a1 = ldfrag_f32(Xp, 16, HH, k0, lane);
    #pragma unroll
    for(int j = 0; j < 4; ++j){
      s8v bb = ldfrag_bf(As, ncol0 + (j<<4), HH, k0, lane);
      acc[0][j] = mfma16(a0, bb, acc[0][j]);
      acc[1][j] = mfma16(a1, bb, acc[1][j]);
    }
  }
  #pragma unroll
  for(int mi=0;mi<2;++mi)
  #pragma unroll
  for(int j=0;j<4;++j)
  #pragma unroll
  for(int r=0;r<4;++r){
    int rown = (mi<<4) + (q<<2) + r;
    int col  = ncol0 + (j<<4) + c0;
    fstage[(size_t)rown*HH + col] = acc[mi][j][r];
  }
  RAWBAR();
  #pragma unroll
  for(int rr = 0; rr < 8; ++rr){                    // coalesced add + store
    int fi = tid + (rr << 9);
    int rn = fi >> 7, col = (fi & 127) << 2;
    f4v v = *(const f4v*)(fstage + (size_t)rn*HH + col);
    f4v xc = *(const f4v*)(Xc + (size_t)rn*HH + col);
    v = v + xc;
    *(f4v*)(Out + (size_t)rn*HH + col) = v;
  }
}

// ---------------- out2 = out1 (fallback path only) ----------------
__global__ __launch_bounds__(256) void k_dup(const float* __restrict__ a, float* __restrict__ b, int n4){
  for(int i = blockIdx.x*256 + threadIdx.x; i < n4; i += gridDim.x*256)
    ((f4v*)b)[i] = ((const f4v*)a)[i];
}

extern "C" void kernel_launch(void* const* d_in, const int* in_sizes, int n_in,
                              void* d_out, int out_size, void* d_ws, size_t ws_size,
                              hipStream_t stream) {
  const float* x       = (const float*)d_in[0];  // [32,2048,256] fp32
  const float* initial = (const float*)d_in[1];  // [32,512]
  const float* Wih     = (const float*)d_in[2];  // [512,256]
  const float* bih     = (const float*)d_in[3];  // [512]
  const float* Whh     = (const float*)d_in[4];  // [512,512]
  float* out1 = (float*)d_out;
  float* out2 = out1 + (size_t)NB*TT*HH;

  const size_t MSZ = (size_t)HH*HH;
  short* mats  = (short*)d_ws;                   // 11 slots: W^(2^i), i=0..10
  short* matsT = mats + 11*MSZ;
  short* Wihb  = matsT + 11*MSZ;                 // [512,256] bf16
  float* Y0 = (float*)(Wihb + (size_t)HH*II);    // NCH boundary states [256][32][512] fp32
  float* Y1 = out1;                              // KS ping-pong scratch aliases out1 (pre-scan2 only)
  short* projw = (short*)(Y0 + (size_t)NCH*NB*HH);
  size_t need = (size_t)((char*)(projw + (size_t)NB*TT*HH) - (char*)d_ws);
  bool dual = ws_size >= need;                   // ws big enough to host projF -> dual-store, no dup
  short* projF = dual ? projw : (short*)out2;

  auto M = [&](int i){ return mats  + (size_t)i*MSZ; };
  auto T = [&](int i){ return matsT + (size_t)i*MSZ; };

  k_init_p1<<<dim3(8,8), 256, 0, stream>>>(Whh, M(0), T(0));
  k_cvt<<<dim3(64), 256, 0, stream>>>(Wih, Wihb, HH*II);

  // squaring chain: M(i+1) = M(i)^2  ->  W^2, W^4, ..., W^1024
  ProdArgs pa;
  for(int i = 0; i < 10; ++i){
    pa.A[0] = M(i); pa.Bt[0] = T(i); pa.C[0] = M(i+1); pa.Ct[0] = T(i+1);
    k_prod<<<dim3(8,4,1), 256, 0, stream>>>(pa);
  }

  k_projT<<<dim3(TT), 512, 0, stream>>>(x, Wihb, bih, initial, projF, Y0);    // projF + Y0[0]=h0
  k_scan<0,0><<<dim3(NCH), 512, 0, stream>>>(projF, M(0), nullptr, Y0, nullptr);

  // Kogge-Stone over 256 boundary states: level l uses A^s = W^(8*2^l) = M(3+l)
  float* Ya = Y0; float* Yb = Y1;
  for(int l = 0; l < 8; ++l){
    k_ks<<<dim3(NCH), 512, 0, stream>>>(Ya, Yb, M(3 + l), 1 << l);
    float* tsw = Ya; Ya = Yb; Yb = tsw;
  }
  // 8 swaps -> final boundary states back in Y0

  if(dual){
    k_scan<1,1><<<dim3(NCH), 512, 0, stream>>>(projF, M(0), Y0, out1, out2);  // both copies direct
  } else {
    k_scan<1,0><<<dim3(NCH), 512, 0, stream>>>(projF, M(0), Y0, out1, out1);
    k_dup<<<dim3(2048), 256, 0, stream>>>(out1, out2, NB*TT*HH/4);
  }
}